// Round 7
// baseline (322.094 us; speedup 1.0000x reference)
//
#include <hip/hip_runtime.h>

#define NN 40000
#define NE 320000
#define C 256
#define KORD 5
#define KT 1280          // fused K = 5 * 256

typedef __attribute__((ext_vector_type(8))) short short8;   // 8 x bf16 (4 VGPR)
typedef __attribute__((ext_vector_type(4))) float floatx4;  // 4 x f32
typedef unsigned short bf16_t;

__device__ __forceinline__ bf16_t f2bf(float f) {
    union { float f; unsigned u; } v; v.f = f;
    unsigned r = v.u + 0x7fffu + ((v.u >> 16) & 1u);  // RTNE
    return (bf16_t)(r >> 16);
}
__device__ __forceinline__ float bf2f(bf16_t h) {
    union { unsigned u; float f; } v; v.u = ((unsigned)h) << 16;
    return v.f;
}

#define GLL16(gsrc, ldst)                                                        \
    __builtin_amdgcn_global_load_lds(                                            \
        (const __attribute__((address_space(1))) void*)(gsrc),                   \
        (__attribute__((address_space(3))) void*)(ldst), 16, 0, 0)

// ---------------- graph preprocessing ----------------

__global__ void count_kernel(const int* __restrict__ ei,
                             int* __restrict__ deg_keep,
                             int* __restrict__ cnt_all) {
    int e = blockIdx.x * 256 + threadIdx.x;
    if (e >= NE) return;
    int r = ei[e];
    int c = ei[NE + e];
    atomicAdd(&cnt_all[r], 1);
    if (r != c) atomicAdd(&deg_keep[r], 1);
}

__global__ void scan1_kernel(const int* __restrict__ cnt,
                             int* __restrict__ incl,
                             int* __restrict__ bsum) {
    __shared__ int s[256];
    int t = threadIdx.x;
    int idx = blockIdx.x * 256 + t;
    int v = (idx < NN) ? cnt[idx] : 0;
    s[t] = v;
    __syncthreads();
    for (int off = 1; off < 256; off <<= 1) {
        int add = (t >= off) ? s[t - off] : 0;
        __syncthreads();
        s[t] += add;
        __syncthreads();
    }
    if (idx < NN) incl[idx] = s[t];
    if (t == 255) bsum[blockIdx.x] = s[255];
}

__global__ void scan2_kernel(int* __restrict__ bsum, int nb) {
    __shared__ int s[256];
    int t = threadIdx.x;
    int v = (t < nb) ? bsum[t] : 0;
    s[t] = v;
    __syncthreads();
    for (int off = 1; off < 256; off <<= 1) {
        int add = (t >= off) ? s[t - off] : 0;
        __syncthreads();
        s[t] += add;
        __syncthreads();
    }
    if (t < nb) bsum[t] = s[t] - v;   // exclusive
}

__global__ void scan3_kernel(const int* __restrict__ cnt,
                             const int* __restrict__ incl,
                             const int* __restrict__ bexcl,
                             int* __restrict__ row_ptr,
                             int* __restrict__ cursor) {
    int idx = blockIdx.x * 256 + threadIdx.x;
    if (idx == 0) row_ptr[NN] = NE;
    if (idx >= NN) return;
    int rp = incl[idx] - cnt[idx] + bexcl[blockIdx.x];
    row_ptr[idx] = rp;
    cursor[idx]  = rp;
}

// fill CSR; D^{-1/2} computed inline from deg (dis kernel folded in)
__global__ void fill_kernel(const int* __restrict__ ei,
                            const float* __restrict__ ew,
                            const int* __restrict__ deg,
                            int* __restrict__ cursor,
                            int* __restrict__ csr_col,
                            float* __restrict__ csr_val) {
    int e = blockIdx.x * 256 + threadIdx.x;
    if (e >= NE) return;
    int r = ei[e];
    int c = ei[NE + e];
    int pos = atomicAdd(&cursor[r], 1);
    float w = (r != c) ? ew[e] : 0.0f;     // removed self-loops -> weight 0
    int dr = deg[r], dc = deg[c];
    float fr = (dr > 0) ? rsqrtf((float)dr) : 0.0f;
    float fc = (dc > 0) ? rsqrtf((float)dc) : 0.0f;
    csr_col[pos] = c;
    csr_val[pos] = -fr * w * fc;
}

// convert x (fp32 [NN][256]) into bf16 A-chunk 0 of [NN][KT]
__global__ void convx_kernel(const float* __restrict__ x, bf16_t* __restrict__ abf) {
    int i = blockIdx.x * 256 + threadIdx.x;
    if (i >= NN * 64) return;
    int n = i >> 6, cg = i & 63;
    float4 f = *(const float4*)&x[(size_t)n * C + cg * 4];
    ushort4 h;
    h.x = f2bf(f.x); h.y = f2bf(f.y); h.z = f2bf(f.z); h.w = f2bf(f.w);
    *(ushort4*)&abf[(size_t)n * KT + cg * 4] = h;
}

// LDS-tiled transpose+convert: W[kt(1280)][n(256)] fp32 -> WT[n][kt] bf16.
// 64x64 tiles; reads and writes both coalesced; tile stride 65 -> conflict-free.
__global__ void wt_kernel(const float* __restrict__ W, bf16_t* __restrict__ WT) {
    __shared__ float tile[64][65];
    int k0 = blockIdx.x * 64;   // kt block (20)
    int n0 = blockIdx.y * 64;   // n block (4)
    int tx = threadIdx.x & 63, ty = threadIdx.x >> 6;   // ty 0..3
#pragma unroll
    for (int i = 0; i < 16; ++i) {
        int k = ty * 16 + i;
        tile[k][tx] = W[(size_t)(k0 + k) * 256 + n0 + tx];
    }
    __syncthreads();
#pragma unroll
    for (int i = 0; i < 16; ++i) {
        int n = ty * 16 + i;
        WT[(size_t)(n0 + n) * KT + k0 + tx] = f2bf(tile[tx][n]);
    }
}

// ---------------- SpMM v3 (bf16 state, multi-node waves, dual-edge loads) ----------------
// outb[n][:] = bf16( alpha * sum_j val[j]*Vb[col[j]][:] - (use_sub ? subb[n][:] : 0) )
// Block = 16 nodes; row_ptr staged in LDS once. Wave handles 4 nodes serially.
// 32 lanes cover one row (16 B = 8 channels per lane); lane halves process two
// edges per wave-load; __shfl_xor(.,32) combines. Unroll x2 -> 4 edges in flight.
__global__ __launch_bounds__(256)
void spmm_kernel(const bf16_t* __restrict__ Vb,
                 const bf16_t* __restrict__ subb,
                 const int* __restrict__ row_ptr,
                 const int* __restrict__ csr_col,
                 const float* __restrict__ csr_val,
                 bf16_t* __restrict__ outb,
                 float alpha, int use_sub) {
    __shared__ int rp[17];
    int tid = threadIdx.x;
    int n0 = blockIdx.x * 16;
    if (tid < 17) rp[tid] = row_ptr[n0 + tid];
    __syncthreads();
    int wave = tid >> 6;
    int lane = tid & 63;
    int half = lane >> 5;        // 0 or 1: which edge of the pair
    int l32  = lane & 31;
    int ce   = l32 * 8;          // channel base (8 channels = 16 B)

#pragma unroll
    for (int i = 0; i < 4; ++i) {
        int local = wave * 4 + i;
        int n  = n0 + local;
        int j0 = rp[local], j1 = rp[local + 1];
        float acc[8] = {0, 0, 0, 0, 0, 0, 0, 0};
        int j = j0;
        for (; j + 4 <= j1; j += 4) {
            int   e0 = j + half,     e1 = j + 2 + half;
            int   c0 = csr_col[e0],  c1 = csr_col[e1];
            float w0 = csr_val[e0],  w1 = csr_val[e1];
            uint4 v0 = *(const uint4*)&Vb[(size_t)c0 * KT + ce];
            uint4 v1 = *(const uint4*)&Vb[(size_t)c1 * KT + ce];
            const bf16_t* p0 = (const bf16_t*)&v0;
            const bf16_t* p1 = (const bf16_t*)&v1;
#pragma unroll
            for (int k = 0; k < 8; ++k)
                acc[k] += w0 * bf2f(p0[k]) + w1 * bf2f(p1[k]);
        }
        if (j + 2 <= j1) {
            int   e = j + half;
            int   c = csr_col[e];
            float w = csr_val[e];
            uint4 v = *(const uint4*)&Vb[(size_t)c * KT + ce];
            const bf16_t* pv = (const bf16_t*)&v;
#pragma unroll
            for (int k = 0; k < 8; ++k) acc[k] += w * bf2f(pv[k]);
            j += 2;
        }
        if (j < j1) {                         // odd leftover edge: half 1 contributes 0
            int   c = csr_col[j];
            float w = half ? 0.0f : csr_val[j];
            uint4 v = *(const uint4*)&Vb[(size_t)c * KT + ce];
            const bf16_t* pv = (const bf16_t*)&v;
#pragma unroll
            for (int k = 0; k < 8; ++k) acc[k] += w * bf2f(pv[k]);
        }
#pragma unroll
        for (int k = 0; k < 8; ++k) acc[k] += __shfl_xor(acc[k], 32);
        if (half == 0) {
            union { ushort us[8]; uint4 v; } r;
            if (use_sub) {
                uint4 sv = *(const uint4*)&subb[(size_t)n * KT + ce];
                const bf16_t* ps = (const bf16_t*)&sv;
#pragma unroll
                for (int k = 0; k < 8; ++k) r.us[k] = f2bf(alpha * acc[k] - bf2f(ps[k]));
            } else {
#pragma unroll
                for (int k = 0; k < 8; ++k) r.us[k] = f2bf(alpha * acc[k]);
            }
            *(uint4*)&outb[(size_t)n * KT + ce] = r.v;
        }
    }
}

// ---------------- fused bf16 MFMA GEMM (unchanged from R6) ----------------
__global__ __launch_bounds__(256, 5)
void gemm_mfma(const bf16_t* __restrict__ Abf,  // [NN][KT]
               const bf16_t* __restrict__ WT,   // [256][KT]
               const float* __restrict__ bias,
               float* __restrict__ out) {
    __shared__ bf16_t smem[12288];  // As = [0,4096), Bs = [4096,12288) elements
    int tid = threadIdx.x;
    int w = tid >> 6, lane = tid & 63;
    int m0 = blockIdx.x * 64;
    int n0 = blockIdx.y * 128;
    int wm = w & 1, wn = w >> 1;
    int quad = lane >> 4, l16 = lane & 15, l7 = l16 & 7;

    const bf16_t* srcbase[6];
#pragma unroll
    for (int j = 0; j < 6; ++j) {
        int gi = (w * 6 + j) * 64 + lane;           // 0..1535
        int isB = gi >= 512;
        int t  = isB ? gi - 512 : gi;
        int row = t >> 3;                           // A: 0..63, B: 0..127
        int pg = t & 7;
        int g  = pg ^ (row & 7);                    // physical k-granule slot
        srcbase[j] = (isB ? WT + (size_t)(n0 + row) * KT
                          : Abf + (size_t)(m0 + row) * KT) + g * 8;
    }

    int arowb = wm * 32 + l16;
    int browb = wn * 64 + l16;

    floatx4 acc[2][4] = {};

    for (int k0 = 0; k0 < KT; k0 += 64) {
        __syncthreads();
#pragma unroll
        for (int j = 0; j < 6; ++j)
            GLL16(srcbase[j] + k0, &smem[(w * 6 + j) * 512]);
        __syncthreads();

#pragma unroll
        for (int c = 0; c < 2; ++c) {
            int gp   = (c * 4 + quad) ^ l7;
            int aoff = (arowb * 8 + gp) * 8;
            int boff = 4096 + (browb * 8 + gp) * 8;
            short8 af[2], bfr[4];
#pragma unroll
            for (int mt = 0; mt < 2; ++mt) af[mt]  = *(const short8*)&smem[aoff + mt * 1024];
#pragma unroll
            for (int nt = 0; nt < 4; ++nt) bfr[nt] = *(const short8*)&smem[boff + nt * 1024];
#pragma unroll
            for (int mt = 0; mt < 2; ++mt)
#pragma unroll
                for (int nt = 0; nt < 4; ++nt)
                    acc[mt][nt] = __builtin_amdgcn_mfma_f32_16x16x32_bf16(
                        af[mt], bfr[nt], acc[mt][nt], 0, 0, 0);
        }
    }

#pragma unroll
    for (int nt = 0; nt < 4; ++nt) {
        int n = n0 + wn * 64 + nt * 16 + l16;
        float bv = bias[n];
#pragma unroll
        for (int mt = 0; mt < 2; ++mt) {
            int mbase = m0 + wm * 32 + mt * 16 + quad * 4;
#pragma unroll
            for (int r = 0; r < 4; ++r)
                out[(size_t)(mbase + r) * C + n] = acc[mt][nt][r] + bv;
        }
    }
}

// ---------------- launch ----------------

extern "C" void kernel_launch(void* const* d_in, const int* in_sizes, int n_in,
                              void* d_out, int out_size, void* d_ws, size_t ws_size,
                              hipStream_t stream) {
    const float* x    = (const float*)d_in[0];
    const int*   ei   = (const int*)d_in[1];
    const float* ew   = (const float*)d_in[2];
    const float* W    = (const float*)d_in[3];   // [5][256][256]
    const float* bias = (const float*)d_in[4];
    float* out = (float*)d_out;

    char* p = (char*)d_ws;
    auto carve = [&](size_t bytes) {
        char* q = p;
        p += (bytes + 255) & ~(size_t)255;
        return q;
    };
    int*    deg     = (int*)   carve(NN * 4);
    int*    cnt     = (int*)   carve(NN * 4);
    int*    incl    = (int*)   carve(NN * 4);
    int*    bsum    = (int*)   carve(256 * 4);
    int*    row_ptr = (int*)   carve((NN + 1) * 4);
    int*    cursor  = (int*)   carve(NN * 4);
    int*    csr_col = (int*)   carve(NE * 4);
    float*  csr_val = (float*) carve(NE * 4);
    bf16_t* abf     = (bf16_t*)carve((size_t)NN * KT * 2);   // fused bf16 A (recursion state)
    bf16_t* WT      = (bf16_t*)carve((size_t)C * KT * 2);    // W transposed bf16
    (void)ws_size; (void)n_in; (void)in_sizes; (void)out_size;

    const int NB_E = (NE + 255) / 256;   // 1250
    const int NB_N = (NN + 255) / 256;   // 157

    hipMemsetAsync(deg, 0, NN * 4, stream);
    hipMemsetAsync(cnt, 0, NN * 4, stream);

    count_kernel<<<NB_E, 256, 0, stream>>>(ei, deg, cnt);
    scan1_kernel<<<NB_N, 256, 0, stream>>>(cnt, incl, bsum);
    scan2_kernel<<<1, 256, 0, stream>>>(bsum, NB_N);
    scan3_kernel<<<NB_N, 256, 0, stream>>>(cnt, incl, bsum, row_ptr, cursor);
    fill_kernel<<<NB_E, 256, 0, stream>>>(ei, ew, deg, cursor, csr_col, csr_val);

    convx_kernel<<<(NN * 64 + 255) / 256, 256, 0, stream>>>(x, abf);
    {
        dim3 tg(20, 4);
        wt_kernel<<<tg, 256, 0, stream>>>(W, WT);
    }

    // Chebyshev recursion, bf16 state in abf chunks 0..4 (chunk k at abf + k*256)
    spmm_kernel<<<NN / 16, 256, 0, stream>>>(abf + 0 * 256, nullptr, row_ptr, csr_col,
                                             csr_val, abf + 1 * 256, 1.0f, 0);
    spmm_kernel<<<NN / 16, 256, 0, stream>>>(abf + 1 * 256, abf + 0 * 256, row_ptr,
                                             csr_col, csr_val, abf + 2 * 256, 2.0f, 1);
    spmm_kernel<<<NN / 16, 256, 0, stream>>>(abf + 2 * 256, abf + 1 * 256, row_ptr,
                                             csr_col, csr_val, abf + 3 * 256, 2.0f, 1);
    spmm_kernel<<<NN / 16, 256, 0, stream>>>(abf + 3 * 256, abf + 2 * 256, row_ptr,
                                             csr_col, csr_val, abf + 4 * 256, 2.0f, 1);

    // fused GEMM: out = abf @ WT^T + bias
    dim3 ggrid(625, 2);
    gemm_mfma<<<ggrid, 256, 0, stream>>>(abf, WT, bias, out);
}